// Round 9
// baseline (594.934 us; speedup 1.0000x reference)
//
#include <hip/hip_runtime.h>
#include <hip/hip_bf16.h>
#include <cmath>

typedef unsigned short u16;
typedef __attribute__((ext_vector_type(8))) short short8;
typedef __attribute__((ext_vector_type(4))) float f32x4;

#define DM 1024
#define NH 16
#define DH 64
#define DFF 4096
#define BB 4
#define TT 2048
#define MROWS (BB*TT)

__device__ __forceinline__ float bu2f(u16 u) {
    union { float f; unsigned v; } c; c.v = ((unsigned)u) << 16; return c.f;
}
__device__ __forceinline__ u16 f2bu(float f) {
    __hip_bfloat16 h = __float2bfloat16(f);
    union { __hip_bfloat16 h; u16 u; } c; c.h = h; return c.u;
}
__device__ __forceinline__ void async_copy16(const u16* g, u16* l) {
    __builtin_amdgcn_global_load_lds((const __attribute__((address_space(1))) void*)g,
                                     (__attribute__((address_space(3))) void*)l, 16, 0, 0);
}

// ---------------- LayerNorm: fp32 in -> bf16 out ----------------
__global__ void ln_kernel(const float* __restrict__ x, const float* __restrict__ gamma,
                          const float* __restrict__ beta, u16* __restrict__ out)
{
    int row = blockIdx.x;
    int tid = threadIdx.x;
    float4 v4 = ((const float4*)(x + (size_t)row * DM))[tid];
    float v[4] = { v4.x, v4.y, v4.z, v4.w };
    float s = v[0] + v[1] + v[2] + v[3];
    float ss = v[0]*v[0] + v[1]*v[1] + v[2]*v[2] + v[3]*v[3];
    #pragma unroll
    for (int o = 32; o > 0; o >>= 1) { s += __shfl_down(s, o); ss += __shfl_down(ss, o); }
    __shared__ float red[8];
    int w = tid >> 6;
    if ((tid & 63) == 0) { red[w] = s; red[4 + w] = ss; }
    __syncthreads();
    s  = red[0] + red[1] + red[2] + red[3];
    ss = red[4] + red[5] + red[6] + red[7];
    float mu  = s * (1.0f / DM);
    float var = ss * (1.0f / DM) - mu * mu;
    float rstd = rsqrtf(var + 1e-5f);
    float4 g4 = ((const float4*)gamma)[tid];
    float4 b4 = ((const float4*)beta)[tid];
    float g[4] = { g4.x, g4.y, g4.z, g4.w };
    float b[4] = { b4.x, b4.y, b4.z, b4.w };
    ushort4 o4;
    u16* op = (u16*)&o4;
    #pragma unroll
    for (int i = 0; i < 4; i++) op[i] = f2bu((v[i] - mu) * rstd * g[i] + b[i]);
    ((ushort4*)(out + (size_t)row * DM))[tid] = o4;
}

// ---------------- Transposes + fp32->bf16 ----------------
__global__ void transpose4_f2b(const float* __restrict__ w0, const float* __restrict__ w1,
                               const float* __restrict__ w2, const float* __restrict__ w3,
                               u16* __restrict__ outQKV, u16* __restrict__ outO)
{
    __shared__ u16 tile[32][33];
    const float* in = (blockIdx.z == 0) ? w0 : (blockIdx.z == 1) ? w1
                     : (blockIdx.z == 2) ? w2 : w3;
    u16* out = (blockIdx.z < 3) ? (outQKV + (size_t)blockIdx.z * DM * DM) : outO;
    int bx = blockIdx.x * 32;
    int by = blockIdx.y * 32;
    int tx = threadIdx.x, ty = threadIdx.y;  // 32 x 8
    #pragma unroll
    for (int i = 0; i < 32; i += 8)
        tile[ty + i][tx] = f2bu(in[(size_t)(by + ty + i) * DM + bx + tx]);
    __syncthreads();
    #pragma unroll
    for (int i = 0; i < 32; i += 8)
        out[(size_t)(bx + ty + i) * DM + by + tx] = tile[tx][ty + i];
}

__global__ void transpose_f2b(const float* __restrict__ in, u16* __restrict__ out,
                              int R, int C)
{
    __shared__ u16 tile[32][33];
    int bx = blockIdx.x * 32;
    int by = blockIdx.y * 32;
    int tx = threadIdx.x, ty = threadIdx.y;  // 32 x 8
    #pragma unroll
    for (int i = 0; i < 32; i += 8)
        tile[ty + i][tx] = f2bu(in[(size_t)(by + ty + i) * C + bx + tx]);
    __syncthreads();
    #pragma unroll
    for (int i = 0; i < 32; i += 8)
        out[(size_t)(bx + ty + i) * R + by + tx] = tile[tx][ty + i];
}

// ---------------- GEMM: BK=64, XOR-swizzled LDS (conflict-free frag reads) ----------------
// LDS row r holds global col-group (p ^ (r&7)) at position p (8-elem groups).
// Frag read col = ((ks*4+quad) ^ (lm&7))*8 — lane-constant, zero inner VALU.
#define BM 128
#define BN 128
#define BK 64

template<int EPI>
__global__ void gemm_bt(
    const u16* __restrict__ A, const u16* __restrict__ Bt,
    const float* __restrict__ bias, const float* __restrict__ bias2,
    const float* __restrict__ bias3, void* __restrict__ Cv,
    const float* __restrict__ res, const float* __restrict__ x0,
    const float* __restrict__ gate, int M, int N, int K)
{
    __shared__ __align__(16) u16 As[BM * BK];
    __shared__ __align__(16) u16 Bs[BN * BK];
    int tid = threadIdx.x;
    int lane = tid & 63, wave = tid >> 6;
    int wm = (wave & 1) * 64, wn = (wave >> 1) * 64;
    int lm = lane & 15, quad = lane >> 4;
    size_t row0 = (size_t)blockIdx.x * BM;
    size_t col0 = (size_t)blockIdx.y * BN;

    int sr = tid >> 3;                              // 0..31
    int scol = (((tid & 7) ^ (sr & 7)) * 8);        // swizzled source col
    const u16* Ag = A  + (row0 + sr) * (size_t)K + scol;
    const u16* Bg = Bt + (col0 + sr) * (size_t)K + scol;
    u16* Asl = As + tid * 8;
    u16* Bsl = Bs + tid * 8;

    // lane-constant swizzled frag-read cols for ks=0,1
    int fc0 = ((0 * 4 + quad) ^ (lm & 7)) * 8;
    int fc1 = ((1 * 4 + quad) ^ (lm & 7)) * 8;

    f32x4 acc[4][4];
    #pragma unroll
    for (int i = 0; i < 4; i++)
        #pragma unroll
        for (int j = 0; j < 4; j++)
            acc[i][j] = (f32x4){0.f, 0.f, 0.f, 0.f};

    for (int k0 = 0; k0 < K; k0 += BK) {
        __syncthreads();
        async_copy16(Ag + k0,                  Asl);
        async_copy16(Ag + (size_t)32 * K + k0, Asl + 32 * BK);
        async_copy16(Ag + (size_t)64 * K + k0, Asl + 64 * BK);
        async_copy16(Ag + (size_t)96 * K + k0, Asl + 96 * BK);
        async_copy16(Bg + k0,                  Bsl);
        async_copy16(Bg + (size_t)32 * K + k0, Bsl + 32 * BK);
        async_copy16(Bg + (size_t)64 * K + k0, Bsl + 64 * BK);
        async_copy16(Bg + (size_t)96 * K + k0, Bsl + 96 * BK);
        __syncthreads();
        #pragma unroll
        for (int ks = 0; ks < 2; ks++) {
            int fc = ks ? fc1 : fc0;
            short8 af[4], bfr[4];
            #pragma unroll
            for (int t = 0; t < 4; t++) {
                af[t]  = *(const short8*)&As[(wm + t * 16 + lm) * BK + fc];
                bfr[t] = *(const short8*)&Bs[(wn + t * 16 + lm) * BK + fc];
            }
            #pragma unroll
            for (int mt = 0; mt < 4; mt++)
                #pragma unroll
                for (int nt = 0; nt < 4; nt++)
                    acc[mt][nt] = __builtin_amdgcn_mfma_f32_16x16x32_bf16(
                        af[mt], bfr[nt], acc[mt][nt], 0, 0, 0);
        }
    }

    u16*   C16 = (u16*)Cv;
    float* Cf  = (float*)Cv;

    const float* bb = bias;
    size_t csub = 0;
    if (EPI == 0 && bias2 != nullptr) {
        size_t cbase = col0 + wn;
        if (cbase >= 2048)      { bb = bias3; csub = 2048; }
        else if (cbase >= 1024) { bb = bias2; csub = 1024; }
    }

    #pragma unroll
    for (int mt = 0; mt < 4; mt++) {
        #pragma unroll
        for (int nt = 0; nt < 4; nt++) {
            #pragma unroll
            for (int r = 0; r < 4; r++) {
                size_t row = row0 + wm + mt * 16 + quad * 4 + r;
                size_t col = col0 + wn + nt * 16 + lm;
                size_t idx = row * (size_t)N + col;
                float v = acc[mt][nt][r] + bb[col - csub];
                if (EPI == 0) {
                    C16[idx] = f2bu(v);
                } else if (EPI == 1) {
                    Cf[idx] = v + res[idx];
                } else if (EPI == 2) {
                    v = 0.5f * v * (1.0f + erff(v * 0.70710678118f));
                    C16[idx] = f2bu(v);
                } else {
                    float xv  = x0[idx];
                    float x1v = res[idx];
                    float g   = gate[row >> 11];
                    Cf[idx] = xv + g * (x1v + v - xv);
                }
            }
        }
    }
}

// ---------------- MFMA flash attention v6: single 64-row tiles, queue-fed ----------------
// 2048 blocks (heavy-first), 5 blocks/CU resident -> dispatcher load-balances.
// S^T = K*Q^T swap; fixed-max softmax; row-sum via ones B-frag.
#define AVS 72

__global__ __launch_bounds__(256, 5) void attn_mfma(
    const u16* __restrict__ QKV, u16* __restrict__ ctx)
{
    __shared__ __align__(16) u16 Kl[64][AVS];      // [key][dim]
    __shared__ __align__(16) u16 Vt[64][AVS];      // [dim][key]
    __shared__ __align__(16) u16 Pl[4][16][AVS];   // per-wave P[q][k]

    const int LD = 3 * DM;
    int tid = threadIdx.x, lane = tid & 63, w = tid >> 6;
    int lm = lane & 15, quad = lane >> 4;

    int bi = blockIdx.x;
    int tcur = 31 - (bi & 31);         // heavy tiles first
    int h = (bi >> 5) & 15, b = bi >> 9;

    const size_t hoff = (size_t)h * DH;
    const u16* Qp = QKV + (size_t)b * TT * LD + hoff;
    const u16* Kp = Qp + DM;
    const u16* Vp = Qp + 2 * DM;

    int nch = tcur + 1;
    int q0 = tcur * 64;
    int qw = q0 + w * 16;
    int qv = qw + lm;                  // this lane's query row (S^T layout)

    // Q frag (register layout doubles as MFMA B operand)
    short8 a0 = *(const short8*)(Qp + (size_t)(qw + lm) * LD + quad * 8);
    short8 a1 = *(const short8*)(Qp + (size_t)(qw + lm) * LD + 32 + quad * 8);

    int kkey = tid & 63, kdim = (tid >> 6) * 16;       // K: 1 key x 16 dims
    int vkey = (tid & 31) * 2, vdim = (tid >> 5) * 8;  // V: 2 keys x 8 dims

    const u16* kb0 = Kp + (size_t)kkey * LD + kdim;
    const u16* vb0 = Vp + (size_t)vkey * LD + vdim;
    const u16* vb1 = Vp + (size_t)(vkey + 1) * LD + vdim;

    const float sc = 0.18033688011f;   // log2(e)/8
    const float FM = 24.0f;            // fixed max (exp2 domain)
    const short s1 = (short)0x3F80;    // bf16 1.0
    const short8 ones = (short8){s1, s1, s1, s1, s1, s1, s1, s1};

    uint4 kr0 = *(const uint4*)(kb0);
    uint4 kr1 = *(const uint4*)(kb0 + 8);
    uint4 vr0 = *(const uint4*)(vb0);
    uint4 vr1 = *(const uint4*)(vb1);

    f32x4 o[4], o5;
    #pragma unroll
    for (int ds = 0; ds < 4; ds++) o[ds] = (f32x4){0.f, 0.f, 0.f, 0.f};
    o5 = (f32x4){0.f, 0.f, 0.f, 0.f};

    for (int c = 0; c < nch; c++) {
        int kb = c * 64;
        __syncthreads();
        *(uint4*)&Kl[kkey][kdim]     = kr0;
        *(uint4*)&Kl[kkey][kdim + 8] = kr1;
        {
            const u16* p0 = (const u16*)&vr0;
            const u16* p1 = (const u16*)&vr1;
            #pragma unroll
            for (int j = 0; j < 8; j++) {
                ushort2 pk = { p0[j], p1[j] };
                *(ushort2*)&Vt[vdim + j][vkey] = pk;
            }
        }
        __syncthreads();

        // prefetch next chunk (scalar offset)
        {
            size_t offn = (c + 1 < nch) ? (size_t)(c + 1) * 64 * LD : 0;
            kr0 = *(const uint4*)(kb0 + offn);
            kr1 = *(const uint4*)(kb0 + offn + 8);
            vr0 = *(const uint4*)(vb0 + offn);
            vr1 = *(const uint4*)(vb1 + offn);
        }

        // S^T = K Q^T
        f32x4 s[4];
        #pragma unroll
        for (int ks = 0; ks < 4; ks++) s[ks] = (f32x4){0.f, 0.f, 0.f, 0.f};
        #pragma unroll
        for (int ks = 0; ks < 4; ks++) {
            short8 k0 = *(const short8*)&Kl[ks * 16 + lm][quad * 8];
            short8 k1 = *(const short8*)&Kl[ks * 16 + lm][32 + quad * 8];
            s[ks] = __builtin_amdgcn_mfma_f32_16x16x32_bf16(k0, a0, s[ks], 0, 0, 0);
            s[ks] = __builtin_amdgcn_mfma_f32_16x16x32_bf16(k1, a1, s[ks], 0, 0, 0);
        }

        // P = exp2(s*sc - FM); causal mask -> 0; packed b64 write
        bool mz = (kb + 63 > qw);
        #pragma unroll
        for (int ks = 0; ks < 4; ks++) {
            int kbase = kb + ks * 16 + quad * 4;
            ushort4 pk;
            u16* pp = (u16*)&pk;
            #pragma unroll
            for (int r = 0; r < 4; r++) {
                float v = s[ks][r] * sc - FM;
                if (mz && (kbase + r > qv)) v = -INFINITY;
                pp[r] = f2bu(exp2f(v));
            }
            *(ushort4*)&Pl[w][lm][ks * 16 + quad * 4] = pk;
        }

        // ctx += P V ; l += P * ones
        #pragma unroll
        for (int kc = 0; kc < 2; kc++) {
            short8 ap = *(const short8*)&Pl[w][lm][kc * 32 + quad * 8];
            #pragma unroll
            for (int ds = 0; ds < 4; ds++) {
                short8 bv = *(const short8*)&Vt[ds * 16 + lm][kc * 32 + quad * 8];
                o[ds] = __builtin_amdgcn_mfma_f32_16x16x32_bf16(ap, bv, o[ds], 0, 0, 0);
            }
            o5 = __builtin_amdgcn_mfma_f32_16x16x32_bf16(ap, ones, o5, 0, 0, 0);
        }
    }

    // epilogue
    float inv[4];
    #pragma unroll
    for (int r = 0; r < 4; r++) inv[r] = 1.0f / o5[r];
    #pragma unroll
    for (int ds = 0; ds < 4; ds++)
        #pragma unroll
        for (int r = 0; r < 4; r++) {
            size_t row = (size_t)(b * TT + qw + quad * 4 + r);
            ctx[row * DM + hoff + ds * 16 + lm] = f2bu(o[ds][r] * inv[r]);
        }
}

extern "C" void kernel_launch(void* const* d_in, const int* in_sizes, int n_in,
                              void* d_out, int out_size, void* d_ws, size_t ws_size,
                              hipStream_t stream)
{
    const float* x    = (const float*)d_in[0];
    const float* gate = (const float*)d_in[1];
    const float* Wq   = (const float*)d_in[2];
    const float* bq   = (const float*)d_in[3];
    const float* Wk   = (const float*)d_in[4];
    const float* bk   = (const float*)d_in[5];
    const float* Wv   = (const float*)d_in[6];
    const float* bv   = (const float*)d_in[7];
    const float* Wo   = (const float*)d_in[8];
    const float* bo   = (const float*)d_in[9];
    const float* W1   = (const float*)d_in[10];
    const float* b1   = (const float*)d_in[11];
    const float* W2   = (const float*)d_in[12];
    const float* b2   = (const float*)d_in[13];
    const float* gamma1 = (const float*)d_in[14];
    const float* beta1  = (const float*)d_in[15];
    const float* gamma2 = (const float*)d_in[16];
    const float* beta2  = (const float*)d_in[17];
    float* out = (float*)d_out;

    char* ws = (char*)d_ws;
    const size_t MB = 1024 * 1024;
    u16* WtQKV = (u16*)(ws + 0 * MB);
    u16* WtO   = (u16*)(ws + 6 * MB);
    u16* Wt1   = (u16*)(ws + 8 * MB);
    u16* Wt2   = (u16*)(ws + 16 * MB);
    u16* h     = (u16*)(ws + 24 * MB);
    u16* ctx   = (u16*)(ws + 24 * MB);
    u16* QKVb  = (u16*)(ws + 40 * MB);
    float* x1  = (float*)(ws + 40 * MB);
    u16* h2    = (u16*)(ws + 72 * MB);
    u16* ff    = (u16*)(ws + 88 * MB);

    dim3 tb(32, 8);
    transpose4_f2b<<<dim3(32, 32, 4), tb, 0, stream>>>(Wq, Wk, Wv, Wo, WtQKV, WtO);
    transpose_f2b<<<dim3(DFF / 32, DM / 32), tb, 0, stream>>>(W1, Wt1, DM, DFF);
    transpose_f2b<<<dim3(DM / 32, DFF / 32), tb, 0, stream>>>(W2, Wt2, DFF, DM);

    ln_kernel<<<MROWS, 256, 0, stream>>>(x, gamma1, beta1, h);

    gemm_bt<0><<<dim3(MROWS / BM, 3 * DM / BN), 256, 0, stream>>>(
        h, WtQKV, bq, bk, bv, QKVb, nullptr, nullptr, nullptr, MROWS, 3 * DM, DM);

    attn_mfma<<<BB * NH * 32, 256, 0, stream>>>(QKVb, ctx);

    gemm_bt<1><<<dim3(MROWS / BM, DM / BN), 256, 0, stream>>>(
        ctx, WtO, bo, nullptr, nullptr, x1, x, nullptr, nullptr, MROWS, DM, DM);

    ln_kernel<<<MROWS, 256, 0, stream>>>(x1, gamma2, beta2, h2);

    gemm_bt<2><<<dim3(MROWS / BM, DFF / BN), 256, 0, stream>>>(
        h2, Wt1, b1, nullptr, nullptr, ff, nullptr, nullptr, nullptr, MROWS, DFF, DM);

    gemm_bt<3><<<dim3(MROWS / BM, DM / BN), 256, 0, stream>>>(
        ff, Wt2, b2, nullptr, nullptr, out, x1, x, gate, MROWS, DM, DFF);
}

// Round 10
// 538.635 us; speedup vs baseline: 1.1045x; 1.1045x over previous
//
#include <hip/hip_runtime.h>
#include <hip/hip_bf16.h>
#include <cmath>

typedef unsigned short u16;
typedef __attribute__((ext_vector_type(8))) short short8;
typedef __attribute__((ext_vector_type(4))) float f32x4;

#define DM 1024
#define NH 16
#define DH 64
#define DFF 4096
#define BB 4
#define TT 2048
#define MROWS (BB*TT)

__device__ __forceinline__ float bu2f(u16 u) {
    union { float f; unsigned v; } c; c.v = ((unsigned)u) << 16; return c.f;
}
__device__ __forceinline__ u16 f2bu(float f) {
    __hip_bfloat16 h = __float2bfloat16(f);
    union { __hip_bfloat16 h; u16 u; } c; c.h = h; return c.u;
}
__device__ __forceinline__ void async_copy16(const u16* g, u16* l) {
    __builtin_amdgcn_global_load_lds((const __attribute__((address_space(1))) void*)g,
                                     (__attribute__((address_space(3))) void*)l, 16, 0, 0);
}

// ---------------- LayerNorm: fp32 in -> bf16 out ----------------
__global__ void ln_kernel(const float* __restrict__ x, const float* __restrict__ gamma,
                          const float* __restrict__ beta, u16* __restrict__ out)
{
    int row = blockIdx.x;
    int tid = threadIdx.x;
    float4 v4 = ((const float4*)(x + (size_t)row * DM))[tid];
    float v[4] = { v4.x, v4.y, v4.z, v4.w };
    float s = v[0] + v[1] + v[2] + v[3];
    float ss = v[0]*v[0] + v[1]*v[1] + v[2]*v[2] + v[3]*v[3];
    #pragma unroll
    for (int o = 32; o > 0; o >>= 1) { s += __shfl_down(s, o); ss += __shfl_down(ss, o); }
    __shared__ float red[8];
    int w = tid >> 6;
    if ((tid & 63) == 0) { red[w] = s; red[4 + w] = ss; }
    __syncthreads();
    s  = red[0] + red[1] + red[2] + red[3];
    ss = red[4] + red[5] + red[6] + red[7];
    float mu  = s * (1.0f / DM);
    float var = ss * (1.0f / DM) - mu * mu;
    float rstd = rsqrtf(var + 1e-5f);
    float4 g4 = ((const float4*)gamma)[tid];
    float4 b4 = ((const float4*)beta)[tid];
    float g[4] = { g4.x, g4.y, g4.z, g4.w };
    float b[4] = { b4.x, b4.y, b4.z, b4.w };
    ushort4 o4;
    u16* op = (u16*)&o4;
    #pragma unroll
    for (int i = 0; i < 4; i++) op[i] = f2bu((v[i] - mu) * rstd * g[i] + b[i]);
    ((ushort4*)(out + (size_t)row * DM))[tid] = o4;
}

// ---------------- Transposes + fp32->bf16 ----------------
__global__ void transpose4_f2b(const float* __restrict__ w0, const float* __restrict__ w1,
                               const float* __restrict__ w2, const float* __restrict__ w3,
                               u16* __restrict__ outQKV, u16* __restrict__ outO)
{
    __shared__ u16 tile[32][33];
    const float* in = (blockIdx.z == 0) ? w0 : (blockIdx.z == 1) ? w1
                     : (blockIdx.z == 2) ? w2 : w3;
    u16* out = (blockIdx.z < 3) ? (outQKV + (size_t)blockIdx.z * DM * DM) : outO;
    int bx = blockIdx.x * 32;
    int by = blockIdx.y * 32;
    int tx = threadIdx.x, ty = threadIdx.y;  // 32 x 8
    #pragma unroll
    for (int i = 0; i < 32; i += 8)
        tile[ty + i][tx] = f2bu(in[(size_t)(by + ty + i) * DM + bx + tx]);
    __syncthreads();
    #pragma unroll
    for (int i = 0; i < 32; i += 8)
        out[(size_t)(bx + ty + i) * DM + by + tx] = tile[tx][ty + i];
}

__global__ void transpose_f2b(const float* __restrict__ in, u16* __restrict__ out,
                              int R, int C)
{
    __shared__ u16 tile[32][33];
    int bx = blockIdx.x * 32;
    int by = blockIdx.y * 32;
    int tx = threadIdx.x, ty = threadIdx.y;  // 32 x 8
    #pragma unroll
    for (int i = 0; i < 32; i += 8)
        tile[ty + i][tx] = f2bu(in[(size_t)(by + ty + i) * C + bx + tx]);
    __syncthreads();
    #pragma unroll
    for (int i = 0; i < 32; i += 8)
        out[(size_t)(bx + ty + i) * R + by + tx] = tile[tx][ty + i];
}

// ---------------- GEMM: BK=64, XOR-swizzled LDS (conflict-free frag reads) ----------------
#define BM 128
#define BN 128
#define BK 64

template<int EPI>
__global__ void gemm_bt(
    const u16* __restrict__ A, const u16* __restrict__ Bt,
    const float* __restrict__ bias, const float* __restrict__ bias2,
    const float* __restrict__ bias3, void* __restrict__ Cv,
    const float* __restrict__ res, const float* __restrict__ x0,
    const float* __restrict__ gate, int M, int N, int K)
{
    __shared__ __align__(16) u16 As[BM * BK];
    __shared__ __align__(16) u16 Bs[BN * BK];
    int tid = threadIdx.x;
    int lane = tid & 63, wave = tid >> 6;
    int wm = (wave & 1) * 64, wn = (wave >> 1) * 64;
    int lm = lane & 15, quad = lane >> 4;
    size_t row0 = (size_t)blockIdx.x * BM;
    size_t col0 = (size_t)blockIdx.y * BN;

    int sr = tid >> 3;                              // 0..31
    int scol = (((tid & 7) ^ (sr & 7)) * 8);        // swizzled source col
    const u16* Ag = A  + (row0 + sr) * (size_t)K + scol;
    const u16* Bg = Bt + (col0 + sr) * (size_t)K + scol;
    u16* Asl = As + tid * 8;
    u16* Bsl = Bs + tid * 8;

    int fc0 = ((0 * 4 + quad) ^ (lm & 7)) * 8;
    int fc1 = ((1 * 4 + quad) ^ (lm & 7)) * 8;

    f32x4 acc[4][4];
    #pragma unroll
    for (int i = 0; i < 4; i++)
        #pragma unroll
        for (int j = 0; j < 4; j++)
            acc[i][j] = (f32x4){0.f, 0.f, 0.f, 0.f};

    for (int k0 = 0; k0 < K; k0 += BK) {
        __syncthreads();
        async_copy16(Ag + k0,                  Asl);
        async_copy16(Ag + (size_t)32 * K + k0, Asl + 32 * BK);
        async_copy16(Ag + (size_t)64 * K + k0, Asl + 64 * BK);
        async_copy16(Ag + (size_t)96 * K + k0, Asl + 96 * BK);
        async_copy16(Bg + k0,                  Bsl);
        async_copy16(Bg + (size_t)32 * K + k0, Bsl + 32 * BK);
        async_copy16(Bg + (size_t)64 * K + k0, Bsl + 64 * BK);
        async_copy16(Bg + (size_t)96 * K + k0, Bsl + 96 * BK);
        __syncthreads();
        #pragma unroll
        for (int ks = 0; ks < 2; ks++) {
            int fc = ks ? fc1 : fc0;
            short8 af[4], bfr[4];
            #pragma unroll
            for (int t = 0; t < 4; t++) {
                af[t]  = *(const short8*)&As[(wm + t * 16 + lm) * BK + fc];
                bfr[t] = *(const short8*)&Bs[(wn + t * 16 + lm) * BK + fc];
            }
            #pragma unroll
            for (int mt = 0; mt < 4; mt++)
                #pragma unroll
                for (int nt = 0; nt < 4; nt++)
                    acc[mt][nt] = __builtin_amdgcn_mfma_f32_16x16x32_bf16(
                        af[mt], bfr[nt], acc[mt][nt], 0, 0, 0);
        }
    }

    u16*   C16 = (u16*)Cv;
    float* Cf  = (float*)Cv;

    const float* bb = bias;
    size_t csub = 0;
    if (EPI == 0 && bias2 != nullptr) {
        size_t cbase = col0 + wn;
        if (cbase >= 2048)      { bb = bias3; csub = 2048; }
        else if (cbase >= 1024) { bb = bias2; csub = 1024; }
    }

    #pragma unroll
    for (int mt = 0; mt < 4; mt++) {
        #pragma unroll
        for (int nt = 0; nt < 4; nt++) {
            #pragma unroll
            for (int r = 0; r < 4; r++) {
                size_t row = row0 + wm + mt * 16 + quad * 4 + r;
                size_t col = col0 + wn + nt * 16 + lm;
                size_t idx = row * (size_t)N + col;
                float v = acc[mt][nt][r] + bb[col - csub];
                if (EPI == 0) {
                    C16[idx] = f2bu(v);
                } else if (EPI == 1) {
                    Cf[idx] = v + res[idx];
                } else if (EPI == 2) {
                    v = 0.5f * v * (1.0f + erff(v * 0.70710678118f));
                    C16[idx] = f2bu(v);
                } else {
                    float xv  = x0[idx];
                    float x1v = res[idx];
                    float g   = gate[row >> 11];
                    Cf[idx] = xv + g * (x1v + v - xv);
                }
            }
        }
    }
}

// ---------------- MFMA flash attention (r8 paired version, verified 118us) ----------------
// Paired 64-row tiles {31-p, p}: every block exactly 33 chunks (uniform lock-step).
// S^T = K*Q^T swap -> packed b64 P-writes; fixed-max softmax; row-sum via ones B-frag.
#define AVS 72

__global__ __launch_bounds__(256, 4) void attn_mfma(
    const u16* __restrict__ QKV, u16* __restrict__ ctx)
{
    __shared__ __align__(16) u16 Kl[64][AVS];      // [key][dim]
    __shared__ __align__(16) u16 Vt[64][AVS];      // [dim][key]
    __shared__ __align__(16) u16 Pl[4][16][AVS];   // per-wave P[q][k]

    const int LD = 3 * DM;
    int tid = threadIdx.x, lane = tid & 63, w = tid >> 6;
    int lm = lane & 15, quad = lane >> 4;

    int bi = blockIdx.x;
    int pair = bi & 15, h = (bi >> 4) & 15, b = bi >> 8;
    int t1 = 31 - pair, t2 = pair;

    const size_t hoff = (size_t)h * DH;
    const u16* Qp = QKV + (size_t)b * TT * LD + hoff;
    const u16* Kp = Qp + DM;
    const u16* Vp = Qp + 2 * DM;

    short8 aqA[2], aqB[2];
    #pragma unroll
    for (int dc = 0; dc < 2; dc++) {
        aqA[dc] = *(const short8*)(Qp + (size_t)(t1 * 64 + w * 16 + lm) * LD + dc * 32 + quad * 8);
        aqB[dc] = *(const short8*)(Qp + (size_t)(t2 * 64 + w * 16 + lm) * LD + dc * 32 + quad * 8);
    }

    int kkey = tid & 63, kdim = (tid >> 6) * 16;       // K: 1 key x 16 dims
    int vkey = (tid & 31) * 2, vdim = (tid >> 5) * 8;  // V: 2 keys x 8 dims

    const u16* kb0 = Kp + (size_t)kkey * LD + kdim;
    const u16* vb0 = Vp + (size_t)vkey * LD + vdim;
    const u16* vb1 = Vp + (size_t)(vkey + 1) * LD + vdim;

    const float sc = 0.18033688011f;   // log2(e)/8
    const float FM = 24.0f;            // fixed max (exp2 domain)
    const short s1 = (short)0x3F80;    // bf16 1.0
    const short8 ones = (short8){s1, s1, s1, s1, s1, s1, s1, s1};

    uint4 kr0 = *(const uint4*)(kb0);
    uint4 kr1 = *(const uint4*)(kb0 + 8);
    uint4 vr0 = *(const uint4*)(vb0);
    uint4 vr1 = *(const uint4*)(vb1);

    #pragma unroll
    for (int ti = 0; ti < 2; ti++) {
        int tcur = (ti == 0) ? t1 : t2;
        int nch = tcur + 1;
        int q0 = tcur * 64;
        int qw = q0 + w * 16;
        short8 a0 = (ti == 0) ? aqA[0] : aqB[0];
        short8 a1 = (ti == 0) ? aqA[1] : aqB[1];
        int qv = qw + lm;

        f32x4 o[4], o5;
        #pragma unroll
        for (int ds = 0; ds < 4; ds++) o[ds] = (f32x4){0.f, 0.f, 0.f, 0.f};
        o5 = (f32x4){0.f, 0.f, 0.f, 0.f};

        for (int c = 0; c < nch; c++) {
            int kb = c * 64;
            __syncthreads();
            *(uint4*)&Kl[kkey][kdim]     = kr0;
            *(uint4*)&Kl[kkey][kdim + 8] = kr1;
            {
                const u16* p0 = (const u16*)&vr0;
                const u16* p1 = (const u16*)&vr1;
                #pragma unroll
                for (int j = 0; j < 8; j++) {
                    ushort2 pk = { p0[j], p1[j] };
                    *(ushort2*)&Vt[vdim + j][vkey] = pk;
                }
            }
            __syncthreads();

            {
                size_t offn = (c + 1 < nch) ? (size_t)(c + 1) * 64 * LD : 0;
                kr0 = *(const uint4*)(kb0 + offn);
                kr1 = *(const uint4*)(kb0 + offn + 8);
                vr0 = *(const uint4*)(vb0 + offn);
                vr1 = *(const uint4*)(vb1 + offn);
            }

            // S^T = K Q^T
            f32x4 s[4];
            #pragma unroll
            for (int ks = 0; ks < 4; ks++) s[ks] = (f32x4){0.f, 0.f, 0.f, 0.f};
            #pragma unroll
            for (int ks = 0; ks < 4; ks++) {
                short8 k0 = *(const short8*)&Kl[ks * 16 + lm][quad * 8];
                short8 k1 = *(const short8*)&Kl[ks * 16 + lm][32 + quad * 8];
                s[ks] = __builtin_amdgcn_mfma_f32_16x16x32_bf16(k0, a0, s[ks], 0, 0, 0);
                s[ks] = __builtin_amdgcn_mfma_f32_16x16x32_bf16(k1, a1, s[ks], 0, 0, 0);
            }

            // P = exp2(s*sc - FM); causal mask -> 0; packed b64 write
            bool mz = (kb + 63 > qw);
            #pragma unroll
            for (int ks = 0; ks < 4; ks++) {
                int kbase = kb + ks * 16 + quad * 4;
                ushort4 pk;
                u16* pp = (u16*)&pk;
                #pragma unroll
                for (int r = 0; r < 4; r++) {
                    float v = s[ks][r] * sc - FM;
                    if (mz && (kbase + r > qv)) v = -INFINITY;
                    pp[r] = f2bu(exp2f(v));
                }
                *(ushort4*)&Pl[w][lm][ks * 16 + quad * 4] = pk;
            }

            // ctx += P V ; l += P * ones
            #pragma unroll
            for (int kc = 0; kc < 2; kc++) {
                short8 ap = *(const short8*)&Pl[w][lm][kc * 32 + quad * 8];
                #pragma unroll
                for (int ds = 0; ds < 4; ds++) {
                    short8 bv = *(const short8*)&Vt[ds * 16 + lm][kc * 32 + quad * 8];
                    o[ds] = __builtin_amdgcn_mfma_f32_16x16x32_bf16(ap, bv, o[ds], 0, 0, 0);
                }
                o5 = __builtin_amdgcn_mfma_f32_16x16x32_bf16(ap, ones, o5, 0, 0, 0);
            }
        }

        float inv[4];
        #pragma unroll
        for (int r = 0; r < 4; r++) inv[r] = 1.0f / o5[r];
        #pragma unroll
        for (int ds = 0; ds < 4; ds++)
            #pragma unroll
            for (int r = 0; r < 4; r++) {
                size_t row = (size_t)(b * TT + qw + quad * 4 + r);
                ctx[row * DM + hoff + ds * 16 + lm] = f2bu(o[ds][r] * inv[r]);
            }
    }
}

extern "C" void kernel_launch(void* const* d_in, const int* in_sizes, int n_in,
                              void* d_out, int out_size, void* d_ws, size_t ws_size,
                              hipStream_t stream)
{
    const float* x    = (const float*)d_in[0];
    const float* gate = (const float*)d_in[1];
    const float* Wq   = (const float*)d_in[2];
    const float* bq   = (const float*)d_in[3];
    const float* Wk   = (const float*)d_in[4];
    const float* bk   = (const float*)d_in[5];
    const float* Wv   = (const float*)d_in[6];
    const float* bv   = (const float*)d_in[7];
    const float* Wo   = (const float*)d_in[8];
    const float* bo   = (const float*)d_in[9];
    const float* W1   = (const float*)d_in[10];
    const float* b1   = (const float*)d_in[11];
    const float* W2   = (const float*)d_in[12];
    const float* b2   = (const float*)d_in[13];
    const float* gamma1 = (const float*)d_in[14];
    const float* beta1  = (const float*)d_in[15];
    const float* gamma2 = (const float*)d_in[16];
    const float* beta2  = (const float*)d_in[17];
    float* out = (float*)d_out;

    char* ws = (char*)d_ws;
    const size_t MB = 1024 * 1024;
    u16* WtQKV = (u16*)(ws + 0 * MB);
    u16* WtO   = (u16*)(ws + 6 * MB);
    u16* Wt1   = (u16*)(ws + 8 * MB);
    u16* Wt2   = (u16*)(ws + 16 * MB);
    u16* h     = (u16*)(ws + 24 * MB);
    u16* ctx   = (u16*)(ws + 24 * MB);
    u16* QKVb  = (u16*)(ws + 40 * MB);
    float* x1  = (float*)(ws + 40 * MB);
    u16* h2    = (u16*)(ws + 72 * MB);
    u16* ff    = (u16*)(ws + 88 * MB);

    dim3 tb(32, 8);
    transpose4_f2b<<<dim3(32, 32, 4), tb, 0, stream>>>(Wq, Wk, Wv, Wo, WtQKV, WtO);
    transpose_f2b<<<dim3(DFF / 32, DM / 32), tb, 0, stream>>>(W1, Wt1, DM, DFF);
    transpose_f2b<<<dim3(DM / 32, DFF / 32), tb, 0, stream>>>(W2, Wt2, DFF, DM);

    ln_kernel<<<MROWS, 256, 0, stream>>>(x, gamma1, beta1, h);

    gemm_bt<0><<<dim3(MROWS / BM, 3 * DM / BN), 256, 0, stream>>>(
        h, WtQKV, bq, bk, bv, QKVb, nullptr, nullptr, nullptr, MROWS, 3 * DM, DM);

    attn_mfma<<<BB * NH * 16, 256, 0, stream>>>(QKVb, ctx);

    gemm_bt<1><<<dim3(MROWS / BM, DM / BN), 256, 0, stream>>>(
        ctx, WtO, bo, nullptr, nullptr, x1, x, nullptr, nullptr, MROWS, DM, DM);

    ln_kernel<<<MROWS, 256, 0, stream>>>(x1, gamma2, beta2, h2);

    gemm_bt<2><<<dim3(MROWS / BM, DFF / BN), 256, 0, stream>>>(
        h2, Wt1, b1, nullptr, nullptr, ff, nullptr, nullptr, nullptr, MROWS, DFF, DM);

    gemm_bt<3><<<dim3(MROWS / BM, DM / BN), 256, 0, stream>>>(
        ff, Wt2, b2, nullptr, nullptr, out, x1, x, gate, MROWS, DM, DFF);
}